// Round 1
// baseline (398.895 us; speedup 1.0000x reference)
//
#include <hip/hip_runtime.h>

// Problem constants (from reference setup_inputs): S=1024, B=64, H=1024.
#define S_LEN 1024
#define B_N   64
#define H_DIM 1024

// One block per batch element b. Phase 1 reduces masks column b -> pos.
// Phase 2 gathers cur/prev rows of hiddens/cells (or init vectors) and blends.
__global__ __launch_bounds__(256) void lstm_state_gather(
    const float* __restrict__ hiddens,   // (S, B, H)
    const float* __restrict__ cells,     // (S, B, H)
    const float* __restrict__ init_h,    // (H,)
    const float* __restrict__ init_c,    // (H,)
    const int*   __restrict__ masks,     // (S, B)
    const int*   __restrict__ op,        // (B,)
    float*       __restrict__ out)       // [hidden_ret (B,H) | cell_ret (B,H)]
{
    const int b   = blockIdx.x;
    const int tid = threadIdx.x;

    // ---------- phase 1: pos = sum_s masks[s][b] ----------
    int part = 0;
#pragma unroll
    for (int i = 0; i < 4; ++i)
        part += masks[(tid + i * 256) * B_N + b];

    // wave64 shuffle reduction
#pragma unroll
    for (int off = 32; off > 0; off >>= 1)
        part += __shfl_down(part, off, 64);

    __shared__ int warp_sums[4];
    __shared__ int s_pos;
    if ((tid & 63) == 0) warp_sums[tid >> 6] = part;
    __syncthreads();
    if (tid == 0) s_pos = warp_sums[0] + warp_sums[1] + warp_sums[2] + warp_sums[3];
    __syncthreads();

    const int pos  = s_pos;                        // in [0, S]
    const int prev = (pos == 0) ? S_LEN : pos - 1; // mod(pos-1, S+1)

    const float a  = fabsf((float)op[b]);
    const float ca = 1.0f - a;

    // ---------- phase 2: gather + blend (float4 per thread) ----------
    const int    h     = tid * 4;                  // H_DIM/4 == 256 threads
    const size_t row_b = (size_t)b * H_DIM + (size_t)h;
    const size_t plane = (size_t)B_N * H_DIM;

    const float4* curH = (pos == 0)
        ? (const float4*)(init_h + h)
        : (const float4*)(hiddens + (size_t)(pos - 1) * plane + row_b);
    const float4* prvH = (prev == 0)
        ? (const float4*)(init_h + h)
        : (const float4*)(hiddens + (size_t)(prev - 1) * plane + row_b);
    const float4* curC = (pos == 0)
        ? (const float4*)(init_c + h)
        : (const float4*)(cells + (size_t)(pos - 1) * plane + row_b);
    const float4* prvC = (prev == 0)
        ? (const float4*)(init_c + h)
        : (const float4*)(cells + (size_t)(prev - 1) * plane + row_b);

    const float4 ch = *curH;
    const float4 ph = *prvH;
    const float4 cc = *curC;
    const float4 pc = *prvC;

    float4 oh, oc;
    oh.x = ph.x * a + ch.x * ca;
    oh.y = ph.y * a + ch.y * ca;
    oh.z = ph.z * a + ch.z * ca;
    oh.w = ph.w * a + ch.w * ca;
    oc.x = pc.x * a + cc.x * ca;
    oc.y = pc.y * a + cc.y * ca;
    oc.z = pc.z * a + cc.z * ca;
    oc.w = pc.w * a + cc.w * ca;

    *(float4*)(out + row_b)         = oh;
    *(float4*)(out + plane + row_b) = oc;
}

extern "C" void kernel_launch(void* const* d_in, const int* in_sizes, int n_in,
                              void* d_out, int out_size, void* d_ws, size_t ws_size,
                              hipStream_t stream) {
    const float* hiddens = (const float*)d_in[0];
    const float* cells   = (const float*)d_in[1];
    const float* init_h  = (const float*)d_in[2];
    const float* init_c  = (const float*)d_in[3];
    const int*   masks   = (const int*)d_in[4];
    const int*   op      = (const int*)d_in[5];
    float*       out     = (float*)d_out;

    lstm_state_gather<<<B_N, 256, 0, stream>>>(
        hiddens, cells, init_h, init_c, masks, op, out);
}